// Round 14
// baseline (2503.587 us; speedup 1.0000x reference)
//
#include <hip/hip_runtime.h>
#include <hip/hip_bf16.h>

#define LSEQ 384
#define BATCH 32
#define BIGV 1e30f
#define TB_STK 448
#define NN ((size_t)LSEQ * LSEQ)
#define BT 32          // tile size
#define NT 12          // tiles per side (BT*NT = LSEQ)
#define PIT 33         // LDS pitch (conflict-free columns)

__device__ __forceinline__ int detect_mmode_wave(const unsigned char* m0, int lane) {
    unsigned char v = m0[lane & 63];
    unsigned long long big = __ballot(v >= 2);
    unsigned long long off = __ballot((((lane & 63) & 3) != 0) && (v != 0));
    return big ? 2 : (off ? 1 : 0);
}
__device__ __forceinline__ bool mask_read(const void* mask, size_t idx, int mmode) {
    if (mmode == 0) return ((const unsigned int*)mask)[idx] != 0;
    if (mmode == 1) return ((const unsigned char*)mask)[idx] != 0;
    return ((const unsigned short*)mask)[idx] != 0;
}
__device__ __forceinline__ void choice_write(void* mask, size_t idx, int c, int mmode) {
    if (mmode == 0) ((unsigned int*)mask)[idx] = (unsigned int)c;
    else if (mmode == 1) ((unsigned char*)mask)[idx] = (unsigned char)c;
    else ((unsigned short*)mask)[idx] = (unsigned short)c;
}
__device__ __forceinline__ int choice_read(const void* mask, size_t idx, int mmode) {
    if (mmode == 0) return (int)((const unsigned int*)mask)[idx];
    if (mmode == 1) return (int)((const unsigned char*)mask)[idx];
    return (int)((const unsigned short*)mask)[idx];
}

// Tiled DP, one block (1024 thr) per sequence. dp IN-PLACE over e_pair
// (upper = dp[i][j]; shifted mirror at [j][i-1]); choices to mask lower tri.
// bif(i,j) = min(edge1[k in blk I], far[k in middle blks], edge2[k in blk J]).
// far = register-blocked min-plus over finalized tiles (global reads, L1-hot).
// Diagonal tiles dT + current antidiagonal acc tiles live in LDS.
__global__ __launch_bounds__(1024) void dp_kernel(
    float* __restrict__ e_pair, const float* __restrict__ e_unp, void* mask)
{
    __shared__ float dT[NT][BT][PIT];        // 50688 B: diagonal tiles
    __shared__ float acc[NT - 1][BT][PIT];   // 46464 B: current-phase tiles
    __shared__ float brow[NT - 1][BT];       // dp[(I+1)B][JB+lj]
    __shared__ float bcol[NT - 1][BT];       // dp[IB+li][JB-1]
    __shared__ float bcorn[NT - 1];          // dp[(I+1)B][JB-1]
    __shared__ float s_eunp[LSEQ];
    __shared__ int s_mmode;

    const int b = blockIdx.x;
    const int tid = threadIdx.x;
    const int lane = tid & 63;
    const int wv = tid >> 6;
    float* dpG = e_pair + (size_t)b * NN;
    const size_t mb = (size_t)b * NN;

    if (tid < 64) {
        int mm = detect_mmode_wave((const unsigned char*)mask, tid);
        if (tid == 0) s_mmode = mm;
    }
    for (int i = tid; i < LSEQ; i += 1024) {
        float v = e_unp[b * LSEQ + i];
        s_eunp[i] = v;
        dT[i >> 5][i & 31][i & 31] = v;              // dp[i][i]
        dpG[(size_t)i * LSEQ + i] = v;
        if (i > 0) dpG[(size_t)i * LSEQ + i - 1] = v; // mirror
    }
    __syncthreads();
    const int mmode = s_mmode;

    // ---------------- phase 0: diagonal tiles ----------------
    for (int sg = 1; sg < BT; ++sg) {
        const int nc = BT - sg;
        const int tot = NT * nc * 2;
        if (tid < tot) {
            int c = tid >> 1, h = tid & 1;
            int t = c / nc, idx = c % nc;
            int li = idx, lj = idx + sg;
            int i = t * BT + li, j = t * BT + lj;
            float x0 = BIGV, x1 = BIGV, x2 = BIGV;   // h1 -> (e2,opt1,opt2m)
            float e1 = BIGV, opt0 = 0.f;
            if (h == 0) {
                float ea = BIGV, eb = BIGV; int kk = li;
                for (; kk + 1 < lj; kk += 2) {
                    ea = fminf(ea, dT[t][li][kk] + dT[t][kk + 1][lj]);
                    eb = fminf(eb, dT[t][li][kk + 1] + dT[t][kk + 2][lj]);
                }
                for (; kk < lj; ++kk) ea = fminf(ea, dT[t][li][kk] + dT[t][kk + 1][lj]);
                e1 = fminf(ea, eb);
                opt0 = dT[t][li + 1][lj] + s_eunp[i];
            } else {
                x0 = BIGV;                            // no edge2 in-diagonal
                x1 = dT[t][li][lj - 1] + s_eunp[j];   // opt1
                x2 = BIGV;
                if (sg > 4 && mask_read(mask, mb + (size_t)i * LSEQ + j, mmode))
                    x2 = dT[t][li + 1][lj - 1] + dpG[(size_t)i * LSEQ + j]; // orig e_pair
            }
            float y0 = __shfl_xor(x0, 1), y1 = __shfl_xor(x1, 1), y2 = __shfl_xor(x2, 1);
            if (h == 0) {
                float best = fminf(fminf(e1, y0), y2);
                int cch = (best == opt0) ? 0 : (best == y1) ? 1
                         : (best == y2 && y2 < BIGV) ? 2 : 3;
                dT[t][li][lj] = best;
                dpG[(size_t)i * LSEQ + j] = best;
                if (i > 0) dpG[(size_t)j * LSEQ + i - 1] = best;
                choice_write(mask, mb + (size_t)j * LSEQ + i, cch, mmode);
            }
        }
        __syncthreads();
    }

    // ---------------- phases s = 1..NT-1 ----------------
    for (int s = 1; s < NT; ++s) {
        const int nt = NT - s;
        // stage boundaries; init acc (only s==1 needs it; far overwrites for s>=2)
        for (int x = tid; x < nt * BT; x += 1024) {
            int t = x / BT, q = x % BT;
            brow[t][q] = dpG[(size_t)((t + 1) * BT) * LSEQ + (t + s) * BT + q];
            bcol[t][q] = dpG[(size_t)(t * BT + q) * LSEQ + ((t + s) * BT - 1)];
        }
        if (tid < nt)
            bcorn[tid] = (s >= 2)
                ? dpG[(size_t)((tid + 1) * BT) * LSEQ + ((tid + s) * BT - 1)] : BIGV;
        if (s == 1)
            for (int x = tid; x < nt * BT * BT; x += 1024)
                acc[x / (BT * BT)][(x / BT) & 31][x & 31] = BIGV;
        __syncthreads();

        // far: owner-wave per tile, 4x4 register blocking, global f4 (L1-hot)
        if (s >= 2 && wv < nt) {
            const int I = wv, J = wv + s;
            const int r0 = (lane >> 3) << 2, c0 = (lane & 7) << 2;
            float r16[16];
            #pragma unroll
            for (int z = 0; z < 16; ++z) r16[z] = BIGV;
            for (int M = I + 1; M < J; ++M) {
                #pragma unroll
                for (int kq = 0; kq < 8; ++kq) {
                    const int k = M * BT + kq * 4;
                    float4 a0 = *(const float4*)&dpG[(size_t)(I * BT + r0 + 0) * LSEQ + k];
                    float4 a1 = *(const float4*)&dpG[(size_t)(I * BT + r0 + 1) * LSEQ + k];
                    float4 a2 = *(const float4*)&dpG[(size_t)(I * BT + r0 + 2) * LSEQ + k];
                    float4 a3 = *(const float4*)&dpG[(size_t)(I * BT + r0 + 3) * LSEQ + k];
                    float4 b0 = *(const float4*)&dpG[(size_t)(J * BT + c0 + 0) * LSEQ + k];
                    float4 b1 = *(const float4*)&dpG[(size_t)(J * BT + c0 + 1) * LSEQ + k];
                    float4 b2 = *(const float4*)&dpG[(size_t)(J * BT + c0 + 2) * LSEQ + k];
                    float4 b3 = *(const float4*)&dpG[(size_t)(J * BT + c0 + 3) * LSEQ + k];
                    #pragma unroll
                    for (int ri = 0; ri < 4; ++ri) {
                        float4 av = ri == 0 ? a0 : ri == 1 ? a1 : ri == 2 ? a2 : a3;
                        #pragma unroll
                        for (int ci = 0; ci < 4; ++ci) {
                            float4 bv = ci == 0 ? b0 : ci == 1 ? b1 : ci == 2 ? b2 : b3;
                            float m = fminf(fminf(av.x + bv.x, av.y + bv.y),
                                            fminf(av.z + bv.z, av.w + bv.w));
                            r16[ri * 4 + ci] = fminf(r16[ri * 4 + ci], m);
                        }
                    }
                }
            }
            #pragma unroll
            for (int ri = 0; ri < 4; ++ri)
                #pragma unroll
                for (int ci = 0; ci < 4; ++ci)
                    acc[wv][r0 + ri][c0 + ci] = r16[ri * 4 + ci];
        }
        __syncthreads();

        // sweep: local antidiagonals sg = -(BT-1)..BT-1, 2 threads per cell
        for (int sg = -(BT - 1); sg <= BT - 1; ++sg) {
            const int asg = sg < 0 ? -sg : sg;
            const int nc = BT - asg;
            const int tot = nt * nc * 2;
            if (tid < tot) {
                int c = tid >> 1, h = tid & 1;
                int t = c / nc, idx = c % nc;
                int li = sg >= 0 ? idx : idx - sg;
                int lj = li + sg;
                const int I = t, J = t + s;
                int i = I * BT + li, j = J * BT + lj;
                float x0 = BIGV, x1 = BIGV, x2 = BIGV;
                float e1 = BIGV, opt0 = 0.f, farv = BIGV;
                if (h == 0) {
                    float ea = BIGV, eb = BIGV; int kk = li;
                    for (; kk + 1 < BT - 1; kk += 2) {
                        ea = fminf(ea, dT[I][li][kk] + acc[t][kk + 1][lj]);
                        eb = fminf(eb, dT[I][li][kk + 1] + acc[t][kk + 2][lj]);
                    }
                    for (; kk < BT - 1; ++kk)
                        ea = fminf(ea, dT[I][li][kk] + acc[t][kk + 1][lj]);
                    e1 = fminf(fminf(ea, eb), dT[I][li][BT - 1] + brow[t][lj]);
                    opt0 = ((li + 1 < BT) ? acc[t][li + 1][lj] : brow[t][lj]) + s_eunp[i];
                    farv = acc[t][li][lj];
                } else {
                    float ea = BIGV, eb = BIGV; int kk = 0;
                    for (; kk + 1 < lj; kk += 2) {
                        ea = fminf(ea, acc[t][li][kk] + dT[J][kk + 1][lj]);
                        eb = fminf(eb, acc[t][li][kk + 1] + dT[J][kk + 2][lj]);
                    }
                    for (; kk < lj; ++kk)
                        ea = fminf(ea, acc[t][li][kk] + dT[J][kk + 1][lj]);
                    x0 = fminf(ea, eb);                                     // e2
                    x1 = ((lj >= 1) ? acc[t][li][lj - 1] : bcol[t][li]) + s_eunp[j];
                    int d = j - i;
                    if (d > 4 && mask_read(mask, mb + (size_t)i * LSEQ + j, mmode)) {
                        float inner;
                        if (li + 1 < BT) inner = (lj >= 1) ? acc[t][li + 1][lj - 1] : bcol[t][li + 1];
                        else             inner = (lj >= 1) ? brow[t][lj - 1] : bcorn[t];
                        x2 = inner + dpG[(size_t)i * LSEQ + j];             // orig e_pair
                    }
                }
                float y0 = __shfl_xor(x0, 1), y1 = __shfl_xor(x1, 1), y2 = __shfl_xor(x2, 1);
                if (h == 0) {
                    float bif = fminf(fminf(e1, y0), farv);
                    float best = fminf(bif, y2);
                    int cch = (best == opt0) ? 0 : (best == y1) ? 1
                             : (best == y2 && y2 < BIGV) ? 2 : 3;
                    acc[t][li][lj] = best;
                    dpG[(size_t)i * LSEQ + j] = best;
                    if (i > 0) dpG[(size_t)j * LSEQ + i - 1] = best;
                    choice_write(mask, mb + (size_t)j * LSEQ + i, cch, mmode);
                }
            }
            __syncthreads();
        }
    }
}

// Traceback (R12-proven, unchanged): one wave per sequence; choices from mask
// lower tri; c==3 argmin t recomputed with lex (value, smallest-t) 64-wide.
__global__ __launch_bounds__(64) void tb_kernel(
    const float* __restrict__ e_pair, const void* mask, float* __restrict__ out)
{
    const int b = blockIdx.x;
    const int lane = threadIdx.x;
    const float* dp = e_pair + (size_t)b * NN;
    const size_t mb = (size_t)b * NN;
    const int mmode = detect_mmode_wave((const unsigned char*)mask, lane);

    __shared__ short res[LSEQ];
    __shared__ int st[TB_STK];
    for (int l = lane; l < LSEQ; l += 64) res[l] = -1;
    st[0] = (0 << 16) | (LSEQ - 1);
    __syncthreads();

    int sp = 1;
    for (int iter = 0; iter < 4096 && sp > 0; ++iter) {
        --sp;
        int pk = st[sp];
        int i = pk >> 16, j = pk & 0xFFFF;
        if (i >= j) continue;
        int c = choice_read(mask, mb + (size_t)j * LSEQ + i, mmode);
        if (c == 0) { st[sp] = ((i + 1) << 16) | j; ++sp; }
        else if (c == 1) { st[sp] = (i << 16) | (j - 1); ++sp; }
        else if (c == 2) {
            res[i] = (short)j; res[j] = (short)i;
            if (i + 1 <= j - 1) { st[sp] = ((i + 1) << 16) | (j - 1); ++sp; }
        } else {
            const int d = j - i;
            const float* rowi = dp + (size_t)i * LSEQ;
            const float* mrow = dp + (size_t)j * LSEQ;
            float bv = BIGV; int bt = d;
            for (int t = lane; t < d; t += 64) {
                float cc = rowi[i + t] + mrow[i + t];
                if (cc < bv || (cc == bv && t < bt)) { bv = cc; bt = t; }
            }
            for (int m = 32; m > 0; m >>= 1) {
                float ov = __shfl_xor(bv, m, 64);
                int   ot = __shfl_xor(bt, m, 64);
                if (ov < bv || (ov == bv && ot < bt)) { bv = ov; bt = ot; }
            }
            int k = i + bt;
            if (sp < TB_STK - 2) {
                st[sp] = (i << 16) | k; ++sp;
                st[sp] = ((k + 1) << 16) | j; ++sp;
            }
        }
        __syncthreads();
    }

    for (int l = lane; l < LSEQ; l += 64)
        out[b * LSEQ + l] = (float)res[l];
    if (lane == 0)
        out[BATCH * LSEQ + b] = dp[LSEQ - 1];
}

extern "C" void kernel_launch(void* const* d_in, const int* in_sizes, int n_in,
                              void* d_out, int out_size, void* d_ws, size_t ws_size,
                              hipStream_t stream) {
    float* e_pair = (float*)d_in[0];
    const float* e_unp = (const float*)d_in[1];
    void* mask = d_in[2];
    (void)d_ws; (void)ws_size;

    dp_kernel<<<BATCH, 1024, 0, stream>>>(e_pair, e_unp, mask);
    tb_kernel<<<BATCH, 64, 0, stream>>>(e_pair, mask, (float*)d_out);
}

// Round 15
// 2429.666 us; speedup vs baseline: 1.0304x; 1.0304x over previous
//
#include <hip/hip_runtime.h>
#include <hip/hip_bf16.h>

#define LSEQ 384
#define BATCH 32
#define BIGV 1e30f
#define TB_STK 448
#define NN ((size_t)LSEQ * LSEQ)
#define BT 32          // tile size
#define NT 12          // tiles per side (BT*NT = LSEQ)
#define PIT 33         // LDS pitch

__device__ __forceinline__ int detect_mmode_wave(const unsigned char* m0, int lane) {
    unsigned char v = m0[lane & 63];
    unsigned long long big = __ballot(v >= 2);
    unsigned long long off = __ballot((((lane & 63) & 3) != 0) && (v != 0));
    return big ? 2 : (off ? 1 : 0);
}
__device__ __forceinline__ bool mask_read(const void* mask, size_t idx, int mmode) {
    if (mmode == 0) return ((const unsigned int*)mask)[idx] != 0;
    if (mmode == 1) return ((const unsigned char*)mask)[idx] != 0;
    return ((const unsigned short*)mask)[idx] != 0;
}
__device__ __forceinline__ void choice_write(void* mask, size_t idx, int c, int mmode) {
    if (mmode == 0) ((unsigned int*)mask)[idx] = (unsigned int)c;
    else if (mmode == 1) ((unsigned char*)mask)[idx] = (unsigned char)c;
    else ((unsigned short*)mask)[idx] = (unsigned short)c;
}
__device__ __forceinline__ int choice_read(const void* mask, size_t idx, int mmode) {
    if (mmode == 0) return (int)((const unsigned int*)mask)[idx];
    if (mmode == 1) return (int)((const unsigned char*)mask)[idx];
    return (int)((const unsigned short*)mask)[idx];
}

// Tiled DP, one block (768 thr = 12 waves) per sequence, WAVE-PER-TILE:
// all in-tile sweep ordering is wave-internal (lockstep + compiler lgkmcnt),
// so barriers drop from R14's 724 to ~13 (one per phase). Math identical to
// R14 (verified absmax 0): dp IN-PLACE over e_pair (upper = dp[i][j], shifted
// mirror M[j][q]=dp[q+1][j] at [j][q]), choices in mask lower triangle.
// bif = min(edge1[k in blk I], far[middle blks], edge2[k in blk J]).
__global__ __launch_bounds__(768) void dp_kernel(
    float* __restrict__ e_pair, const float* __restrict__ e_unp, void* mask)
{
    __shared__ float dT[NT][BT][PIT];        // diagonal tiles (finalized ph.0)
    __shared__ float cur[NT - 1][BT][PIT];   // per-wave current tile
    __shared__ float brow[NT - 1][BT];       // dp[(I+1)B][JB+q]
    __shared__ float bcol[NT - 1][BT];       // dp[IB+q][JB-1]
    __shared__ float bcorn[NT - 1];          // dp[(I+1)B][JB-1]
    __shared__ float s_eunp[LSEQ];
    __shared__ int s_mmode;

    const int b = blockIdx.x;
    const int tid = threadIdx.x;
    const int lane = tid & 63;
    const int wv = tid >> 6;
    float* dpG = e_pair + (size_t)b * NN;
    const size_t mb = (size_t)b * NN;

    if (tid < 64) {
        int mm = detect_mmode_wave((const unsigned char*)mask, tid);
        if (tid == 0) s_mmode = mm;
    }
    for (int i = tid; i < LSEQ; i += 768) {
        float v = e_unp[b * LSEQ + i];
        s_eunp[i] = v;
        dT[i >> 5][i & 31][i & 31] = v;               // dp[i][i]
        dpG[(size_t)i * LSEQ + i] = v;
        if (i > 0) dpG[(size_t)i * LSEQ + i - 1] = v; // mirror
    }
    __syncthreads();
    const int mmode = s_mmode;

    // ---------- phase 0: wave t sweeps diagonal tile t (no barriers) ----------
    if (wv < NT) {
        const int t = wv;
        const int idx = lane >> 1, h = lane & 1;
        for (int sg = 1; sg < BT; ++sg) {
            const int nc = BT - sg;
            const bool act = idx < nc;
            const int li = idx, lj = idx + sg;
            const int i = t * BT + li, j = t * BT + lj;
            float e1 = BIGV, opt0 = 0.f, x0 = BIGV, x1 = BIGV, x2 = BIGV;
            if (act) {
                if (h == 0) {
                    float ea = BIGV, eb = BIGV; int kk = li;
                    for (; kk + 1 < lj; kk += 2) {
                        ea = fminf(ea, dT[t][li][kk] + dT[t][kk + 1][lj]);
                        eb = fminf(eb, dT[t][li][kk + 1] + dT[t][kk + 2][lj]);
                    }
                    for (; kk < lj; ++kk) ea = fminf(ea, dT[t][li][kk] + dT[t][kk + 1][lj]);
                    e1 = fminf(ea, eb);
                    opt0 = dT[t][li + 1][lj] + s_eunp[i];
                } else {
                    x1 = dT[t][li][lj - 1] + s_eunp[j];   // opt1
                    if (sg > 4 && mask_read(mask, mb + (size_t)i * LSEQ + j, mmode))
                        x2 = dT[t][li + 1][lj - 1] + dpG[(size_t)i * LSEQ + j]; // orig e_pair
                }
            }
            float y0 = __shfl_xor(x0, 1), y1 = __shfl_xor(x1, 1), y2 = __shfl_xor(x2, 1);
            (void)y0;
            if (act && h == 0) {
                float best = fminf(e1, y2);               // e1 covers opt0/opt1 numerically
                int cch = (best == opt0) ? 0 : (best == y1) ? 1
                         : (best == y2 && y2 < BIGV) ? 2 : 3;
                dT[t][li][lj] = best;
                dpG[(size_t)i * LSEQ + j] = best;
                if (i > 0) dpG[(size_t)j * LSEQ + i - 1] = best;
                choice_write(mask, mb + (size_t)j * LSEQ + i, cch, mmode);
            }
        }
    }
    __syncthreads();

    // ---------- phases s = 1..NT-1: wave w owns tile (w, w+s) ----------
    for (int s = 1; s < NT; ++s) {
        const int nt = NT - s;
        if (wv < nt) {
            const int I = wv, J = wv + s;
            // boundaries (own-wave loads; prior phase visible via barrier)
            if (lane < BT)
                brow[I][lane] = dpG[(size_t)((I + 1) * BT) * LSEQ + J * BT + lane];
            else
                bcol[I][lane - BT] = dpG[(size_t)(I * BT + lane - BT) * LSEQ + J * BT - 1];
            if (lane == 0)
                bcorn[I] = (s >= 2)
                    ? dpG[(size_t)((I + 1) * BT) * LSEQ + J * BT - 1] : BIGV;

            // far-init of cur[I]
            if (s == 1) {
                for (int z = lane; z < BT * PIT; z += 64)
                    cur[I][z / PIT][z % PIT] = BIGV;
            } else {
                const int r0 = (lane >> 3) << 2, c0 = (lane & 7) << 2;
                float r16[16];
                #pragma unroll
                for (int z = 0; z < 16; ++z) r16[z] = BIGV;
                for (int M = I + 1; M < J; ++M) {
                    #pragma unroll
                    for (int kq = 0; kq < 8; ++kq) {
                        const int k = M * BT + kq * 4;
                        float4 a0 = *(const float4*)&dpG[(size_t)(I * BT + r0 + 0) * LSEQ + k];
                        float4 a1 = *(const float4*)&dpG[(size_t)(I * BT + r0 + 1) * LSEQ + k];
                        float4 a2 = *(const float4*)&dpG[(size_t)(I * BT + r0 + 2) * LSEQ + k];
                        float4 a3 = *(const float4*)&dpG[(size_t)(I * BT + r0 + 3) * LSEQ + k];
                        float4 b0 = *(const float4*)&dpG[(size_t)(J * BT + c0 + 0) * LSEQ + k];
                        float4 b1 = *(const float4*)&dpG[(size_t)(J * BT + c0 + 1) * LSEQ + k];
                        float4 b2 = *(const float4*)&dpG[(size_t)(J * BT + c0 + 2) * LSEQ + k];
                        float4 b3 = *(const float4*)&dpG[(size_t)(J * BT + c0 + 3) * LSEQ + k];
                        #pragma unroll
                        for (int ri = 0; ri < 4; ++ri) {
                            float4 av = ri == 0 ? a0 : ri == 1 ? a1 : ri == 2 ? a2 : a3;
                            #pragma unroll
                            for (int ci = 0; ci < 4; ++ci) {
                                float4 bv = ci == 0 ? b0 : ci == 1 ? b1 : ci == 2 ? b2 : b3;
                                float m = fminf(fminf(av.x + bv.x, av.y + bv.y),
                                                fminf(av.z + bv.z, av.w + bv.w));
                                r16[ri * 4 + ci] = fminf(r16[ri * 4 + ci], m);
                            }
                        }
                    }
                }
                #pragma unroll
                for (int ri = 0; ri < 4; ++ri)
                    #pragma unroll
                    for (int ci = 0; ci < 4; ++ci)
                        cur[I][r0 + ri][c0 + ci] = r16[ri * 4 + ci];
            }

            // in-tile sweep: wave-internal only
            const int idx = lane >> 1, h = lane & 1;
            for (int sg = -(BT - 1); sg <= BT - 1; ++sg) {
                const int asg = sg < 0 ? -sg : sg;
                const int nc = BT - asg;
                const bool act = idx < nc;
                const int li = (sg >= 0) ? idx : idx - sg;
                const int lj = li + sg;
                const int i = I * BT + li, j = J * BT + lj;
                float e1 = BIGV, opt0 = 0.f, farv = BIGV;
                float x0 = BIGV, x1 = BIGV, x2 = BIGV;
                if (act) {
                    if (h == 0) {
                        float ea = BIGV, eb = BIGV; int kk = li;
                        for (; kk + 1 < BT - 1; kk += 2) {
                            ea = fminf(ea, dT[I][li][kk] + cur[I][kk + 1][lj]);
                            eb = fminf(eb, dT[I][li][kk + 1] + cur[I][kk + 2][lj]);
                        }
                        for (; kk < BT - 1; ++kk)
                            ea = fminf(ea, dT[I][li][kk] + cur[I][kk + 1][lj]);
                        e1 = fminf(fminf(ea, eb), dT[I][li][BT - 1] + brow[I][lj]);
                        opt0 = ((li + 1 < BT) ? cur[I][li + 1][lj] : brow[I][lj]) + s_eunp[i];
                        farv = cur[I][li][lj];
                    } else {
                        float ea = BIGV, eb = BIGV; int kk = 0;
                        for (; kk + 1 < lj; kk += 2) {
                            ea = fminf(ea, cur[I][li][kk] + dT[J][kk + 1][lj]);
                            eb = fminf(eb, cur[I][li][kk + 1] + dT[J][kk + 2][lj]);
                        }
                        for (; kk < lj; ++kk)
                            ea = fminf(ea, cur[I][li][kk] + dT[J][kk + 1][lj]);
                        x0 = fminf(ea, eb);                                   // e2
                        x1 = ((lj >= 1) ? cur[I][li][lj - 1] : bcol[I][li]) + s_eunp[j];
                        int d = j - i;
                        if (d > 4 && mask_read(mask, mb + (size_t)i * LSEQ + j, mmode)) {
                            float inner;
                            if (li + 1 < BT) inner = (lj >= 1) ? cur[I][li + 1][lj - 1] : bcol[I][li + 1];
                            else             inner = (lj >= 1) ? brow[I][lj - 1] : bcorn[I];
                            x2 = inner + dpG[(size_t)i * LSEQ + j];           // orig e_pair
                        }
                    }
                }
                float y0 = __shfl_xor(x0, 1), y1 = __shfl_xor(x1, 1), y2 = __shfl_xor(x2, 1);
                if (act && h == 0) {
                    float bif = fminf(fminf(e1, y0), farv);
                    float best = fminf(bif, y2);
                    int cch = (best == opt0) ? 0 : (best == y1) ? 1
                             : (best == y2 && y2 < BIGV) ? 2 : 3;
                    cur[I][li][lj] = best;
                    dpG[(size_t)i * LSEQ + j] = best;
                    if (i > 0) dpG[(size_t)j * LSEQ + i - 1] = best;
                    choice_write(mask, mb + (size_t)j * LSEQ + i, cch, mmode);
                }
            }
        }
        __syncthreads();
    }
}

// Traceback (R12-proven, unchanged).
__global__ __launch_bounds__(64) void tb_kernel(
    const float* __restrict__ e_pair, const void* mask, float* __restrict__ out)
{
    const int b = blockIdx.x;
    const int lane = threadIdx.x;
    const float* dp = e_pair + (size_t)b * NN;
    const size_t mb = (size_t)b * NN;
    const int mmode = detect_mmode_wave((const unsigned char*)mask, lane);

    __shared__ short res[LSEQ];
    __shared__ int st[TB_STK];
    for (int l = lane; l < LSEQ; l += 64) res[l] = -1;
    st[0] = (0 << 16) | (LSEQ - 1);
    __syncthreads();

    int sp = 1;
    for (int iter = 0; iter < 4096 && sp > 0; ++iter) {
        --sp;
        int pk = st[sp];
        int i = pk >> 16, j = pk & 0xFFFF;
        if (i >= j) continue;
        int c = choice_read(mask, mb + (size_t)j * LSEQ + i, mmode);
        if (c == 0) { st[sp] = ((i + 1) << 16) | j; ++sp; }
        else if (c == 1) { st[sp] = (i << 16) | (j - 1); ++sp; }
        else if (c == 2) {
            res[i] = (short)j; res[j] = (short)i;
            if (i + 1 <= j - 1) { st[sp] = ((i + 1) << 16) | (j - 1); ++sp; }
        } else {
            const int d = j - i;
            const float* rowi = dp + (size_t)i * LSEQ;
            const float* mrow = dp + (size_t)j * LSEQ;
            float bv = BIGV; int bt = d;
            for (int t = lane; t < d; t += 64) {
                float cc = rowi[i + t] + mrow[i + t];
                if (cc < bv || (cc == bv && t < bt)) { bv = cc; bt = t; }
            }
            for (int m = 32; m > 0; m >>= 1) {
                float ov = __shfl_xor(bv, m, 64);
                int   ot = __shfl_xor(bt, m, 64);
                if (ov < bv || (ov == bv && ot < bt)) { bv = ov; bt = ot; }
            }
            int k = i + bt;
            if (sp < TB_STK - 2) {
                st[sp] = (i << 16) | k; ++sp;
                st[sp] = ((k + 1) << 16) | j; ++sp;
            }
        }
        __syncthreads();
    }

    for (int l = lane; l < LSEQ; l += 64)
        out[b * LSEQ + l] = (float)res[l];
    if (lane == 0)
        out[BATCH * LSEQ + b] = dp[LSEQ - 1];
}

extern "C" void kernel_launch(void* const* d_in, const int* in_sizes, int n_in,
                              void* d_out, int out_size, void* d_ws, size_t ws_size,
                              hipStream_t stream) {
    float* e_pair = (float*)d_in[0];
    const float* e_unp = (const float*)d_in[1];
    void* mask = d_in[2];
    (void)d_ws; (void)ws_size;

    dp_kernel<<<BATCH, 768, 0, stream>>>(e_pair, e_unp, mask);
    tb_kernel<<<BATCH, 64, 0, stream>>>(e_pair, mask, (float*)d_out);
}

// Round 16
// 1603.814 us; speedup vs baseline: 1.5610x; 1.5149x over previous
//
#include <hip/hip_runtime.h>
#include <hip/hip_bf16.h>

#define LSEQ 384
#define BATCH 32
#define BIGV 1e30f
#define TB_STK 448
#define NN ((size_t)LSEQ * LSEQ)
#define BT 32          // tile size
#define NT 12          // tiles per side
#define PIT 33         // LDS pitch

__device__ __forceinline__ int detect_mmode_wave(const unsigned char* m0, int lane) {
    unsigned char v = m0[lane & 63];
    unsigned long long big = __ballot(v >= 2);
    unsigned long long off = __ballot((((lane & 63) & 3) != 0) && (v != 0));
    return big ? 2 : (off ? 1 : 0);
}
__device__ __forceinline__ bool mask_read(const void* mask, size_t idx, int mmode) {
    if (mmode == 0) return ((const unsigned int*)mask)[idx] != 0;
    if (mmode == 1) return ((const unsigned char*)mask)[idx] != 0;
    return ((const unsigned short*)mask)[idx] != 0;
}
__device__ __forceinline__ void choice_write(void* mask, size_t idx, int c, int mmode) {
    if (mmode == 0) ((unsigned int*)mask)[idx] = (unsigned int)c;
    else if (mmode == 1) ((unsigned char*)mask)[idx] = (unsigned char)c;
    else ((unsigned short*)mask)[idx] = (unsigned short)c;
}
__device__ __forceinline__ int choice_read(const void* mask, size_t idx, int mmode) {
    if (mmode == 0) return (int)((const unsigned int*)mask)[idx];
    if (mmode == 1) return (int)((const unsigned char*)mask)[idx];
    return (int)((const unsigned short*)mask)[idx];
}

// Unified per-lane edge reduction: min over kk in [lo,hi) of rowp[kk] +
// colp[kk*PIT]. 4 independent accumulator chains, 8 loads per group in
// flight -> LDS throughput-bound, not latency-bound.
__device__ __forceinline__ float edge_min(const float* rowp, const float* colp,
                                          int lo, int hi) {
    float a0 = BIGV, a1 = BIGV, a2 = BIGV, a3 = BIGV;
    int kk = lo;
    for (; kk + 3 < hi; kk += 4) {
        float r0 = rowp[kk], r1 = rowp[kk + 1], r2 = rowp[kk + 2], r3 = rowp[kk + 3];
        const float* cb = colp + kk * PIT;
        float c0 = cb[0], c1 = cb[PIT], c2 = cb[2 * PIT], c3 = cb[3 * PIT];
        a0 = fminf(a0, r0 + c0); a1 = fminf(a1, r1 + c1);
        a2 = fminf(a2, r2 + c2); a3 = fminf(a3, r3 + c3);
    }
    for (; kk < hi; ++kk) a0 = fminf(a0, rowp[kk] + colp[kk * PIT]);
    return fminf(fminf(a0, a1), fminf(a2, a3));
}

// Tiled DP, one block (768 thr = 12 waves) per sequence, wave-per-tile.
// Math identical to R14/R15 (absmax 0): dp IN-PLACE over e_pair (upper =
// dp[i][j]; shifted mirror M[j][q]=dp[q+1][j]); choices in mask lower tri.
// NEW: per-tile masked pair-energy staged to LDS (epm) so the 724-step sweep
// has ZERO global loads; unified branchless edge loop (no h0/h1 divergence);
// pipelined LDS loads.
__global__ __launch_bounds__(768) void dp_kernel(
    float* __restrict__ e_pair, const float* __restrict__ e_unp, void* mask)
{
    __shared__ float dT[NT][BT][PIT];        // 50688 B diagonal tiles
    __shared__ float cur[NT - 1][BT][PIT];   // 46464 B per-wave current tile
    __shared__ float epm[NT - 1][BT][PIT];   // 46464 B masked pair energies
    __shared__ float brow[NT - 1][BT];
    __shared__ float bcol[NT - 1][BT];
    __shared__ float bcorn[NT - 1];
    __shared__ float s_eunp[LSEQ];
    __shared__ int s_mmode;

    const int b = blockIdx.x;
    const int tid = threadIdx.x;
    const int lane = tid & 63;
    const int wv = tid >> 6;
    float* dpG = e_pair + (size_t)b * NN;
    const size_t mb = (size_t)b * NN;

    if (tid < 64) {
        int mm = detect_mmode_wave((const unsigned char*)mask, tid);
        if (tid == 0) s_mmode = mm;
    }
    for (int i = tid; i < LSEQ; i += 768) {
        float v = e_unp[b * LSEQ + i];
        s_eunp[i] = v;
        dT[i >> 5][i & 31][i & 31] = v;               // dp[i][i]
        dpG[(size_t)i * LSEQ + i] = v;
        if (i > 0) dpG[(size_t)i * LSEQ + i - 1] = v; // mirror
    }
    __syncthreads();
    const int mmode = s_mmode;

    // ---------- phase 0: wave t sweeps diagonal tile t ----------
    if (wv < NT) {
        const int t = wv;
        float* ep0 = (t < NT - 1) ? &epm[t][0][0] : &cur[0][0][0];
        for (int z = lane; z < BT * BT; z += 64) {    // stage masked energies
            int li = z >> 5, lj = z & 31;
            int i = t * BT + li, j = t * BT + lj;
            bool ok = (lj - li > 4) && mask_read(mask, mb + (size_t)i * LSEQ + j, mmode);
            ep0[li * PIT + lj] = ok ? dpG[(size_t)i * LSEQ + j] : BIGV;
        }
        const int idx = lane >> 1, h = lane & 1;
        for (int sg = 1; sg < BT; ++sg) {
            const int nc = BT - sg;
            const bool act = idx < nc;
            const int li = idx, lj = idx + sg;
            const int i = t * BT + li, j = t * BT + lj;
            int lo = li, hi = lj;
            if (!act || h == 1) { lo = 0; hi = 0; }
            float ev = edge_min(&dT[t][li][0], &dT[t][1][lj], lo, hi);
            float e1 = BIGV, opt0 = 0.f, x1 = BIGV, x2 = BIGV;
            if (act) {
                if (h == 0) {
                    e1 = ev;                              // includes opt0(kk=li), opt1(kk=lj-1)
                    opt0 = dT[t][li + 1][lj] + s_eunp[i];
                } else {
                    x1 = dT[t][li][lj - 1] + s_eunp[j];
                    float pe = ep0[li * PIT + lj];
                    if (pe < BIGV) x2 = dT[t][li + 1][lj - 1] + pe;
                }
            }
            float y1 = __shfl_xor(x1, 1), y2 = __shfl_xor(x2, 1);
            if (act && h == 0) {
                float best = fminf(e1, y2);
                int cch = (best == opt0) ? 0 : (best == y1) ? 1
                         : (best == y2 && y2 < BIGV) ? 2 : 3;
                dT[t][li][lj] = best;
                dpG[(size_t)i * LSEQ + j] = best;
                if (i > 0) dpG[(size_t)j * LSEQ + i - 1] = best;
                choice_write(mask, mb + (size_t)j * LSEQ + i, cch, mmode);
            }
        }
    }
    __syncthreads();

    // ---------- phases s = 1..NT-1: wave w owns tile (w, w+s) ----------
    for (int s = 1; s < NT; ++s) {
        const int nt = NT - s;
        if (wv < nt) {
            const int I = wv, J = wv + s;
            if (lane < BT)
                brow[I][lane] = dpG[(size_t)((I + 1) * BT) * LSEQ + J * BT + lane];
            else
                bcol[I][lane - BT] = dpG[(size_t)(I * BT + lane - BT) * LSEQ + J * BT - 1];
            if (lane == 0)
                bcorn[I] = (s >= 2)
                    ? dpG[(size_t)((I + 1) * BT) * LSEQ + J * BT - 1] : BIGV;

            for (int z = lane; z < BT * BT; z += 64) {   // stage masked energies
                int li = z >> 5, lj = z & 31;
                int i = I * BT + li, j = J * BT + lj;
                bool ok = (j - i > 4) && mask_read(mask, mb + (size_t)i * LSEQ + j, mmode);
                epm[I][li][lj] = ok ? dpG[(size_t)i * LSEQ + j] : BIGV;
            }

            // far-init of cur[I] (R15-verified)
            if (s == 1) {
                for (int z = lane; z < BT * PIT; z += 64)
                    cur[I][z / PIT][z % PIT] = BIGV;
            } else {
                const int r0 = (lane >> 3) << 2, c0 = (lane & 7) << 2;
                float r16[16];
                #pragma unroll
                for (int z = 0; z < 16; ++z) r16[z] = BIGV;
                for (int M = I + 1; M < J; ++M) {
                    #pragma unroll
                    for (int kq = 0; kq < 8; ++kq) {
                        const int k = M * BT + kq * 4;
                        float4 a0 = *(const float4*)&dpG[(size_t)(I * BT + r0 + 0) * LSEQ + k];
                        float4 a1 = *(const float4*)&dpG[(size_t)(I * BT + r0 + 1) * LSEQ + k];
                        float4 a2 = *(const float4*)&dpG[(size_t)(I * BT + r0 + 2) * LSEQ + k];
                        float4 a3 = *(const float4*)&dpG[(size_t)(I * BT + r0 + 3) * LSEQ + k];
                        float4 b0 = *(const float4*)&dpG[(size_t)(J * BT + c0 + 0) * LSEQ + k];
                        float4 b1 = *(const float4*)&dpG[(size_t)(J * BT + c0 + 1) * LSEQ + k];
                        float4 b2 = *(const float4*)&dpG[(size_t)(J * BT + c0 + 2) * LSEQ + k];
                        float4 b3 = *(const float4*)&dpG[(size_t)(J * BT + c0 + 3) * LSEQ + k];
                        #pragma unroll
                        for (int ri = 0; ri < 4; ++ri) {
                            float4 av = ri == 0 ? a0 : ri == 1 ? a1 : ri == 2 ? a2 : a3;
                            #pragma unroll
                            for (int ci = 0; ci < 4; ++ci) {
                                float4 bv = ci == 0 ? b0 : ci == 1 ? b1 : ci == 2 ? b2 : b3;
                                float m = fminf(fminf(av.x + bv.x, av.y + bv.y),
                                                fminf(av.z + bv.z, av.w + bv.w));
                                r16[ri * 4 + ci] = fminf(r16[ri * 4 + ci], m);
                            }
                        }
                    }
                }
                #pragma unroll
                for (int ri = 0; ri < 4; ++ri)
                    #pragma unroll
                    for (int ci = 0; ci < 4; ++ci)
                        cur[I][r0 + ri][c0 + ci] = r16[ri * 4 + ci];
            }

            // in-tile sweep: pure LDS, branchless unified edge loop
            const int idx = lane >> 1, h = lane & 1;
            for (int sg = -(BT - 1); sg <= BT - 1; ++sg) {
                const int asg = sg < 0 ? -sg : sg;
                const int nc = BT - asg;
                const bool act = idx < nc;
                const int li = (sg >= 0) ? idx : idx - sg;
                const int lj = li + sg;
                const int i = I * BT + li, j = J * BT + lj;
                const float* rowp; const float* colp; int lo, hi;
                if (h == 0) { rowp = &dT[I][li][0]; colp = &cur[I][1][lj]; lo = li; hi = BT - 1; }
                else        { rowp = &cur[I][li][0]; colp = &dT[J][1][lj]; lo = 0;  hi = lj; }
                if (!act) { lo = 0; hi = 0; }
                float ev = edge_min(rowp, colp, lo, hi);
                float e1 = BIGV, opt0 = 0.f, farv = BIGV;
                float x0 = BIGV, x1 = BIGV, x2 = BIGV;
                if (act) {
                    if (h == 0) {
                        e1 = fminf(ev, dT[I][li][BT - 1] + brow[I][lj]);
                        opt0 = ((li + 1 < BT) ? cur[I][li + 1][lj] : brow[I][lj]) + s_eunp[i];
                        farv = cur[I][li][lj];
                    } else {
                        x0 = ev;
                        x1 = ((lj >= 1) ? cur[I][li][lj - 1] : bcol[I][li]) + s_eunp[j];
                        float pe = epm[I][li][lj];
                        if (pe < BIGV) {
                            float inner = (li + 1 < BT)
                                ? ((lj >= 1) ? cur[I][li + 1][lj - 1] : bcol[I][li + 1])
                                : ((lj >= 1) ? brow[I][lj - 1] : bcorn[I]);
                            x2 = inner + pe;
                        }
                    }
                }
                float y0 = __shfl_xor(x0, 1), y1 = __shfl_xor(x1, 1), y2 = __shfl_xor(x2, 1);
                if (act && h == 0) {
                    float best = fminf(fminf(fminf(e1, y0), farv), y2);
                    int cch = (best == opt0) ? 0 : (best == y1) ? 1
                             : (best == y2 && y2 < BIGV) ? 2 : 3;
                    cur[I][li][lj] = best;
                    dpG[(size_t)i * LSEQ + j] = best;
                    if (i > 0) dpG[(size_t)j * LSEQ + i - 1] = best;
                    choice_write(mask, mb + (size_t)j * LSEQ + i, cch, mmode);
                }
            }
        }
        __syncthreads();
    }
}

// Traceback (R12-proven, unchanged).
__global__ __launch_bounds__(64) void tb_kernel(
    const float* __restrict__ e_pair, const void* mask, float* __restrict__ out)
{
    const int b = blockIdx.x;
    const int lane = threadIdx.x;
    const float* dp = e_pair + (size_t)b * NN;
    const size_t mb = (size_t)b * NN;
    const int mmode = detect_mmode_wave((const unsigned char*)mask, lane);

    __shared__ short res[LSEQ];
    __shared__ int st[TB_STK];
    for (int l = lane; l < LSEQ; l += 64) res[l] = -1;
    st[0] = (0 << 16) | (LSEQ - 1);
    __syncthreads();

    int sp = 1;
    for (int iter = 0; iter < 4096 && sp > 0; ++iter) {
        --sp;
        int pk = st[sp];
        int i = pk >> 16, j = pk & 0xFFFF;
        if (i >= j) continue;
        int c = choice_read(mask, mb + (size_t)j * LSEQ + i, mmode);
        if (c == 0) { st[sp] = ((i + 1) << 16) | j; ++sp; }
        else if (c == 1) { st[sp] = (i << 16) | (j - 1); ++sp; }
        else if (c == 2) {
            res[i] = (short)j; res[j] = (short)i;
            if (i + 1 <= j - 1) { st[sp] = ((i + 1) << 16) | (j - 1); ++sp; }
        } else {
            const int d = j - i;
            const float* rowi = dp + (size_t)i * LSEQ;
            const float* mrow = dp + (size_t)j * LSEQ;
            float bv = BIGV; int bt = d;
            for (int t = lane; t < d; t += 64) {
                float cc = rowi[i + t] + mrow[i + t];
                if (cc < bv || (cc == bv && t < bt)) { bv = cc; bt = t; }
            }
            for (int m = 32; m > 0; m >>= 1) {
                float ov = __shfl_xor(bv, m, 64);
                int   ot = __shfl_xor(bt, m, 64);
                if (ov < bv || (ov == bv && ot < bt)) { bv = ov; bt = ot; }
            }
            int k = i + bt;
            if (sp < TB_STK - 2) {
                st[sp] = (i << 16) | k; ++sp;
                st[sp] = ((k + 1) << 16) | j; ++sp;
            }
        }
        __syncthreads();
    }

    for (int l = lane; l < LSEQ; l += 64)
        out[b * LSEQ + l] = (float)res[l];
    if (lane == 0)
        out[BATCH * LSEQ + b] = dp[LSEQ - 1];
}

extern "C" void kernel_launch(void* const* d_in, const int* in_sizes, int n_in,
                              void* d_out, int out_size, void* d_ws, size_t ws_size,
                              hipStream_t stream) {
    float* e_pair = (float*)d_in[0];
    const float* e_unp = (const float*)d_in[1];
    void* mask = d_in[2];
    (void)d_ws; (void)ws_size;

    dp_kernel<<<BATCH, 768, 0, stream>>>(e_pair, e_unp, mask);
    tb_kernel<<<BATCH, 64, 0, stream>>>(e_pair, mask, (float*)d_out);
}